// Round 5
// baseline (340.688 us; speedup 1.0000x reference)
//
#include <hip/hip_runtime.h>
#include <math.h>

#define BB 16
#define CC 256
#define HH 96
#define WW 96

typedef float floatx4 __attribute__((ext_vector_type(4)));  // native vec for nontemporal store

// ---------------- Kernel 1: 32x32 block-average pool -> pooled (B,C,3,3) ----
// All 9 loads issued up front (9x memory parallelism), one sync total.
__global__ __launch_bounds__(256) void pool_kernel(const float* __restrict__ x,
                                                   float* __restrict__ pooled) {
    const int bc = blockIdx.x;                       // 0 .. B*C-1
    const float4* p4 = (const float4*)(x + (size_t)bc * (HH * WW));
    const int tid  = threadIdx.x;
    const int lane = tid & 63;
    const int wv   = tid >> 6;
    const int r_in = tid >> 3;   // 0..31  row inside a 32x32 block
    const int c4   = tid & 7;    // 0..7   float4 inside the 32-wide block
    __shared__ float red[9][4];

    float s[9];
    #pragma unroll
    for (int bi = 0; bi < 3; ++bi)
        #pragma unroll
        for (int bj = 0; bj < 3; ++bj) {
            float4 v = p4[(bi * 32 + r_in) * 24 + bj * 8 + c4];
            s[bi * 3 + bj] = v.x + v.y + v.z + v.w;
        }

    #pragma unroll
    for (int k = 0; k < 9; ++k) {
        float t = s[k];
        #pragma unroll
        for (int off = 32; off; off >>= 1) t += __shfl_down(t, off, 64);
        if (lane == 0) red[k][wv] = t;
    }
    __syncthreads();
    if (tid < 9)
        pooled[bc * 9 + tid] =
            (red[tid][0] + red[tid][1] + red[tid][2] + red[tid][3]) * (1.0f / 1024.0f);
}

// ---------------- Kernel 2: MLP + softmax(G) + mix -> weight (B,C,9), bias (B,C)
__global__ __launch_bounds__(256) void proj_kernel(
    const float* __restrict__ pooled,
    const float* __restrict__ w1, const float* __restrict__ b1,
    const float* __restrict__ bn_g, const float* __restrict__ bn_b,
    const float* __restrict__ bn_m, const float* __restrict__ bn_v,
    const float* __restrict__ w2, const float* __restrict__ b2,
    const float* __restrict__ w_k, const float* __restrict__ b_k,
    float* __restrict__ weight, float* __restrict__ bias) {
    const int b = blockIdx.x / 10;
    const int p = blockIdx.x % 10;   // 0..8 = pooled pixel, 9 = global mean
    const int tid = threadIdx.x;     // == channel c in the epilogue

    __shared__ __align__(16) float t[CC];
    __shared__ __align__(16) float hbuf[64];
    __shared__ float hpart[256];

    if (p < 9) {
        t[tid] = pooled[(b * CC + tid) * 9 + p];
    } else {
        float s = 0.f;
        #pragma unroll
        for (int q = 0; q < 9; ++q) s += pooled[(b * CC + tid) * 9 + q];
        t[tid] = s * (1.0f / 9.0f);
    }
    __syncthreads();

    // h = w1 @ t  (64 outputs, 4 partial-threads each), float4 dots
    const int o = tid & 63, part = tid >> 6;
    {
        const float4* w1r = (const float4*)(w1 + o * CC + part * 64);
        const float4* tp  = (const float4*)(t + part * 64);
        float acc = 0.f;
        #pragma unroll
        for (int k = 0; k < 16; ++k) {
            float4 a = w1r[k], v = tp[k];
            acc += a.x * v.x + a.y * v.y + a.z * v.z + a.w * v.w;
        }
        hpart[tid] = acc;
    }
    __syncthreads();
    if (tid < 64) {
        float hsum = hpart[tid] + hpart[tid + 64] + hpart[tid + 128] +
                     hpart[tid + 192] + b1[tid];
        float hn = (hsum - bn_m[tid]) * (bn_g[tid] * rsqrtf(bn_v[tid] + 1e-5f)) + bn_b[tid];
        hbuf[tid] = 0.5f * hn * (1.0f + erff(hn * 0.70710678118654752f));
    }
    __syncthreads();

    float vals[4];
    #pragma unroll
    for (int q = 0; q < 4; ++q) {
        const int j = q * 256 + tid;
        const float4* w2r = (const float4*)(w2 + j * 64);
        const float4* hb  = (const float4*)hbuf;
        float a = b2[j];
        #pragma unroll
        for (int k = 0; k < 16; ++k) {
            float4 wv = w2r[k], hv = hb[k];
            a += wv.x * hv.x + wv.y * hv.y + wv.z * hv.z + wv.w * hv.w;
        }
        vals[q] = a;
    }
    float m = fmaxf(fmaxf(vals[0], vals[1]), fmaxf(vals[2], vals[3]));
    float e[4], sum = 0.f;
    #pragma unroll
    for (int q = 0; q < 4; ++q) { e[q] = expf(vals[q] - m); sum += e[q]; }
    const float rinv = 1.0f / sum;

    if (p < 9) {
        float ws = 0.f;
        #pragma unroll
        for (int q = 0; q < 4; ++q)
            ws += (e[q] * rinv) * w_k[(q * CC + tid) * 9 + p];
        weight[(b * CC + tid) * 9 + p] = ws;
    } else {
        float bs = 0.f;
        #pragma unroll
        for (int q = 0; q < 4; ++q)
            bs += (e[q] * rinv) * b_k[q * CC + tid];
        bias[b * CC + tid] = bs;
    }
}

// ---------------- Kernel 3: dynamic depthwise 3x3 conv (SAME) + bias ---------
// LDS-free (R4 verified), now 4x8 patches: per thread 12 float4 + 12 edge
// scalars + 8 NT stores for 32 pixels (VMEM ops/px 1.38 -> 0.69, 2x ILP).
// 2 planes per 576-thread block, 288 threads (24x12 patches) per plane.
// x is L2/L3-hot after pool (R3: FETCH == one x read total); reads are
// cache-served, writes are NT to HBM.
__global__ __launch_bounds__(576) void dwconv_kernel(
    const float* __restrict__ x, const float* __restrict__ weight,
    const float* __restrict__ bias, float* __restrict__ out) {
    const int half = (threadIdx.x >= 288) ? 1 : 0;
    const int bc   = blockIdx.x * 2 + half;
    const int t    = threadIdx.x - half * 288;   // 0..287
    const float* plane = x + (size_t)bc * (HH * WW);
    float* oplane = out + (size_t)bc * (HH * WW);
    const int pr  = t / 12;          // patch row 0..23
    const int pcq = t - pr * 12;     // patch col-pair 0..11
    const int h0  = pr * 4;          // first output row
    const int c0  = pcq * 8;         // first output col (16B aligned)

    float wgt[9];
    #pragma unroll
    for (int k = 0; k < 9; ++k) wgt[k] = weight[bc * 9 + k];
    const float bs = bias[bc];

    // input rows h0-1 .. h0+4, cols c0-1 .. c0+8
    float4 m0[6], m1[6]; float L[6], R[6];
    #pragma unroll
    for (int r = 0; r < 6; ++r) {
        const int gr = h0 + r - 1;
        if (gr >= 0 && gr < HH) {
            const float* row = plane + gr * WW + c0;
            m0[r] = *(const float4*)row;
            m1[r] = *(const float4*)(row + 4);
            L[r] = (c0 > 0)  ? row[-1] : 0.f;
            R[r] = (c0 < 88) ? row[8]  : 0.f;
        } else {
            m0[r] = make_float4(0.f, 0.f, 0.f, 0.f);
            m1[r] = make_float4(0.f, 0.f, 0.f, 0.f);
            L[r] = 0.f;
            R[r] = 0.f;
        }
    }

    #pragma unroll
    for (int orow = 0; orow < 4; ++orow) {
        floatx4 a0 = {bs, bs, bs, bs};
        floatx4 a1 = {bs, bs, bs, bs};
        #pragma unroll
        for (int r = 0; r < 3; ++r) {
            const int rr = orow + r;
            const float wl = wgt[r * 3 + 0], wc = wgt[r * 3 + 1],
                        wr = wgt[r * 3 + 2];
            a0.x += wl * L[rr]     + wc * m0[rr].x + wr * m0[rr].y;
            a0.y += wl * m0[rr].x  + wc * m0[rr].y + wr * m0[rr].z;
            a0.z += wl * m0[rr].y  + wc * m0[rr].z + wr * m0[rr].w;
            a0.w += wl * m0[rr].z  + wc * m0[rr].w + wr * m1[rr].x;
            a1.x += wl * m0[rr].w  + wc * m1[rr].x + wr * m1[rr].y;
            a1.y += wl * m1[rr].x  + wc * m1[rr].y + wr * m1[rr].z;
            a1.z += wl * m1[rr].y  + wc * m1[rr].z + wr * m1[rr].w;
            a1.w += wl * m1[rr].z  + wc * m1[rr].w + wr * R[rr];
        }
        float* orow_p = oplane + (h0 + orow) * WW + c0;
        __builtin_nontemporal_store(a0, (floatx4*)orow_p);
        __builtin_nontemporal_store(a1, (floatx4*)(orow_p + 4));
    }
}

extern "C" void kernel_launch(void* const* d_in, const int* in_sizes, int n_in,
                              void* d_out, int out_size, void* d_ws, size_t ws_size,
                              hipStream_t stream) {
    const float* x    = (const float*)d_in[0];
    const float* w_k  = (const float*)d_in[1];
    const float* b_k  = (const float*)d_in[2];
    const float* w1   = (const float*)d_in[3];
    const float* b1   = (const float*)d_in[4];
    const float* bn_g = (const float*)d_in[5];
    const float* bn_b = (const float*)d_in[6];
    const float* bn_m = (const float*)d_in[7];
    const float* bn_v = (const float*)d_in[8];
    const float* w2   = (const float*)d_in[9];
    const float* b2   = (const float*)d_in[10];
    float* out = (float*)d_out;

    float* pooled = (float*)d_ws;                 // B*C*9 floats
    float* weight = pooled + BB * CC * 9;         // B*C*9 floats
    float* bias   = weight + BB * CC * 9;         // B*C   floats

    pool_kernel<<<BB * CC, 256, 0, stream>>>(x, pooled);
    proj_kernel<<<BB * 10, 256, 0, stream>>>(pooled, w1, b1, bn_g, bn_b, bn_m,
                                             bn_v, w2, b2, w_k, b_k, weight, bias);
    dwconv_kernel<<<BB * CC / 2, 576, 0, stream>>>(x, weight, bias, out);
}

// Round 7
// 311.050 us; speedup vs baseline: 1.0953x; 1.0953x over previous
//
#include <hip/hip_runtime.h>
#include <math.h>

#define BB 16
#define CC 256
#define HH 96
#define WW 96

typedef float floatx4 __attribute__((ext_vector_type(4)));  // native vec for nontemporal store

// ---------------- Kernel 1: 32x32 block-average pool -> pooled (B,C,3,3) ----
// All 9 loads issued up front (9x memory parallelism), one sync total.
__global__ __launch_bounds__(256) void pool_kernel(const float* __restrict__ x,
                                                   float* __restrict__ pooled) {
    const int bc = blockIdx.x;                       // 0 .. B*C-1
    const float4* p4 = (const float4*)(x + (size_t)bc * (HH * WW));
    const int tid  = threadIdx.x;
    const int lane = tid & 63;
    const int wv   = tid >> 6;
    const int r_in = tid >> 3;   // 0..31  row inside a 32x32 block
    const int c4   = tid & 7;    // 0..7   float4 inside the 32-wide block
    __shared__ float red[9][4];

    float s[9];
    #pragma unroll
    for (int bi = 0; bi < 3; ++bi)
        #pragma unroll
        for (int bj = 0; bj < 3; ++bj) {
            float4 v = p4[(bi * 32 + r_in) * 24 + bj * 8 + c4];
            s[bi * 3 + bj] = v.x + v.y + v.z + v.w;
        }

    #pragma unroll
    for (int k = 0; k < 9; ++k) {
        float t = s[k];
        #pragma unroll
        for (int off = 32; off; off >>= 1) t += __shfl_down(t, off, 64);
        if (lane == 0) red[k][wv] = t;
    }
    __syncthreads();
    if (tid < 9)
        pooled[bc * 9 + tid] =
            (red[tid][0] + red[tid][1] + red[tid][2] + red[tid][3]) * (1.0f / 1024.0f);
}

// ---------------- Kernel 2: MLP + softmax(G) + mix -> weight (B,C,9), bias (B,C)
__global__ __launch_bounds__(256) void proj_kernel(
    const float* __restrict__ pooled,
    const float* __restrict__ w1, const float* __restrict__ b1,
    const float* __restrict__ bn_g, const float* __restrict__ bn_b,
    const float* __restrict__ bn_m, const float* __restrict__ bn_v,
    const float* __restrict__ w2, const float* __restrict__ b2,
    const float* __restrict__ w_k, const float* __restrict__ b_k,
    float* __restrict__ weight, float* __restrict__ bias) {
    const int b = blockIdx.x / 10;
    const int p = blockIdx.x % 10;   // 0..8 = pooled pixel, 9 = global mean
    const int tid = threadIdx.x;     // == channel c in the epilogue

    __shared__ __align__(16) float t[CC];
    __shared__ __align__(16) float hbuf[64];
    __shared__ float hpart[256];

    if (p < 9) {
        t[tid] = pooled[(b * CC + tid) * 9 + p];
    } else {
        float s = 0.f;
        #pragma unroll
        for (int q = 0; q < 9; ++q) s += pooled[(b * CC + tid) * 9 + q];
        t[tid] = s * (1.0f / 9.0f);
    }
    __syncthreads();

    // h = w1 @ t  (64 outputs, 4 partial-threads each), float4 dots
    const int o = tid & 63, part = tid >> 6;
    {
        const float4* w1r = (const float4*)(w1 + o * CC + part * 64);
        const float4* tp  = (const float4*)(t + part * 64);
        float acc = 0.f;
        #pragma unroll
        for (int k = 0; k < 16; ++k) {
            float4 a = w1r[k], v = tp[k];
            acc += a.x * v.x + a.y * v.y + a.z * v.z + a.w * v.w;
        }
        hpart[tid] = acc;
    }
    __syncthreads();
    if (tid < 64) {
        float hsum = hpart[tid] + hpart[tid + 64] + hpart[tid + 128] +
                     hpart[tid + 192] + b1[tid];
        float hn = (hsum - bn_m[tid]) * (bn_g[tid] * rsqrtf(bn_v[tid] + 1e-5f)) + bn_b[tid];
        hbuf[tid] = 0.5f * hn * (1.0f + erff(hn * 0.70710678118654752f));
    }
    __syncthreads();

    float vals[4];
    #pragma unroll
    for (int q = 0; q < 4; ++q) {
        const int j = q * 256 + tid;
        const float4* w2r = (const float4*)(w2 + j * 64);
        const float4* hb  = (const float4*)hbuf;
        float a = b2[j];
        #pragma unroll
        for (int k = 0; k < 16; ++k) {
            float4 wv = w2r[k], hv = hb[k];
            a += wv.x * hv.x + wv.y * hv.y + wv.z * hv.z + wv.w * hv.w;
        }
        vals[q] = a;
    }
    float m = fmaxf(fmaxf(vals[0], vals[1]), fmaxf(vals[2], vals[3]));
    float e[4], sum = 0.f;
    #pragma unroll
    for (int q = 0; q < 4; ++q) { e[q] = expf(vals[q] - m); sum += e[q]; }
    const float rinv = 1.0f / sum;

    if (p < 9) {
        float ws = 0.f;
        #pragma unroll
        for (int q = 0; q < 4; ++q)
            ws += (e[q] * rinv) * w_k[(q * CC + tid) * 9 + p];
        weight[(b * CC + tid) * 9 + p] = ws;
    } else {
        float bs = 0.f;
        #pragma unroll
        for (int q = 0; q < 4; ++q)
            bs += (e[q] * rinv) * b_k[q * CC + tid];
        bias[b * CC + tid] = bs;
    }
}

// ---------------- Kernel 3: dynamic depthwise 3x3 conv (SAME) + bias ---------
// LDS-free 4x4-patch version (R4, measured best), re-gridded to 256-thread
// blocks with GLOBAL patch indexing: 8 blocks/CU = 32 waves/CU (100% occupancy
// vs 27/32 for 576-thread blocks). One 4x4 patch per thread; per row one
// 16B-aligned float4 + 2 edge scalars, coalesced across lanes, L1/L2/L3-served
// (x is cache-hot after pool; R3 FETCH proved no HBM re-read). NT stores.
// At most one plane straddle per block -> wgt-load divergence in <=1 wave.
__global__ __launch_bounds__(256) void dwconv_kernel(
    const float* __restrict__ x, const float* __restrict__ weight,
    const float* __restrict__ bias, float* __restrict__ out) {
    const int g  = blockIdx.x * 256 + threadIdx.x;   // global patch id
    const int bc = g / 576;                          // plane 0..4095
    const int p  = g - bc * 576;                     // patch in plane
    const int pr = p / 24;                           // patch row 0..23
    const int pc = p - pr * 24;                      // patch col 0..23
    const int h0 = pr * 4;                           // first output row
    const int c0 = pc * 4;                           // first output col (16B aligned)
    const float* plane = x + (size_t)bc * (HH * WW);
    float* oplane = out + (size_t)bc * (HH * WW);

    float wgt[9];
    #pragma unroll
    for (int k = 0; k < 9; ++k) wgt[k] = weight[bc * 9 + k];
    const float bs = bias[bc];

    // input rows h0-1 .. h0+4
    float4 m[6]; float L[6], R[6];
    #pragma unroll
    for (int r = 0; r < 6; ++r) {
        const int gr = h0 + r - 1;
        if (gr >= 0 && gr < HH) {
            const float* row = plane + gr * WW + c0;
            m[r] = *(const float4*)row;
            L[r] = (pc > 0)  ? row[-1] : 0.f;
            R[r] = (pc < 23) ? row[4]  : 0.f;
        } else {
            m[r] = make_float4(0.f, 0.f, 0.f, 0.f);
            L[r] = 0.f;
            R[r] = 0.f;
        }
    }

    #pragma unroll
    for (int orow = 0; orow < 4; ++orow) {
        floatx4 acc = {bs, bs, bs, bs};
        #pragma unroll
        for (int r = 0; r < 3; ++r) {
            const int rr = orow + r;
            const float wl = wgt[r * 3 + 0], wc = wgt[r * 3 + 1],
                        wr = wgt[r * 3 + 2];
            acc.x += wl * L[rr]   + wc * m[rr].x + wr * m[rr].y;
            acc.y += wl * m[rr].x + wc * m[rr].y + wr * m[rr].z;
            acc.z += wl * m[rr].y + wc * m[rr].z + wr * m[rr].w;
            acc.w += wl * m[rr].z + wc * m[rr].w + wr * R[rr];
        }
        __builtin_nontemporal_store(
            acc, (floatx4*)(oplane + (h0 + orow) * WW + c0));
    }
}

extern "C" void kernel_launch(void* const* d_in, const int* in_sizes, int n_in,
                              void* d_out, int out_size, void* d_ws, size_t ws_size,
                              hipStream_t stream) {
    const float* x    = (const float*)d_in[0];
    const float* w_k  = (const float*)d_in[1];
    const float* b_k  = (const float*)d_in[2];
    const float* w1   = (const float*)d_in[3];
    const float* b1   = (const float*)d_in[4];
    const float* bn_g = (const float*)d_in[5];
    const float* bn_b = (const float*)d_in[6];
    const float* bn_m = (const float*)d_in[7];
    const float* bn_v = (const float*)d_in[8];
    const float* w2   = (const float*)d_in[9];
    const float* b2   = (const float*)d_in[10];
    float* out = (float*)d_out;

    float* pooled = (float*)d_ws;                 // B*C*9 floats
    float* weight = pooled + BB * CC * 9;         // B*C*9 floats
    float* bias   = weight + BB * CC * 9;         // B*C   floats

    pool_kernel<<<BB * CC, 256, 0, stream>>>(x, pooled);
    proj_kernel<<<BB * 10, 256, 0, stream>>>(pooled, w1, b1, bn_g, bn_b, bn_m,
                                             bn_v, w2, b2, w_k, b_k, weight, bias);
    // 4096 planes * 576 patches / 256 threads = 9216 blocks
    dwconv_kernel<<<BB * CC * 576 / 256, 256, 0, stream>>>(x, weight, bias, out);
}

// Round 9
// 310.511 us; speedup vs baseline: 1.0972x; 1.0017x over previous
//
#include <hip/hip_runtime.h>
#include <math.h>

#define BB 16
#define CC 256
#define HH 96
#define WW 96

typedef float floatx4 __attribute__((ext_vector_type(4)));  // native vec for nontemporal store

// ---------------- Kernel 1: 32x32 block-average pool -> pooled (B,C,3,3) ----
// All 9 loads issued up front (9x memory parallelism), one sync total.
__global__ __launch_bounds__(256) void pool_kernel(const float* __restrict__ x,
                                                   float* __restrict__ pooled) {
    const int bc = blockIdx.x;                       // 0 .. B*C-1
    const float4* p4 = (const float4*)(x + (size_t)bc * (HH * WW));
    const int tid  = threadIdx.x;
    const int lane = tid & 63;
    const int wv   = tid >> 6;
    const int r_in = tid >> 3;   // 0..31  row inside a 32x32 block
    const int c4   = tid & 7;    // 0..7   float4 inside the 32-wide block
    __shared__ float red[9][4];

    float s[9];
    #pragma unroll
    for (int bi = 0; bi < 3; ++bi)
        #pragma unroll
        for (int bj = 0; bj < 3; ++bj) {
            float4 v = p4[(bi * 32 + r_in) * 24 + bj * 8 + c4];
            s[bi * 3 + bj] = v.x + v.y + v.z + v.w;
        }

    #pragma unroll
    for (int k = 0; k < 9; ++k) {
        float t = s[k];
        #pragma unroll
        for (int off = 32; off; off >>= 1) t += __shfl_down(t, off, 64);
        if (lane == 0) red[k][wv] = t;
    }
    __syncthreads();
    if (tid < 9)
        pooled[bc * 9 + tid] =
            (red[tid][0] + red[tid][1] + red[tid][2] + red[tid][3]) * (1.0f / 1024.0f);
}

// ---------------- Kernel 2: MLP + softmax(G) + mix -> weight (B,C,9), bias (B,C)
__global__ __launch_bounds__(256) void proj_kernel(
    const float* __restrict__ pooled,
    const float* __restrict__ w1, const float* __restrict__ b1,
    const float* __restrict__ bn_g, const float* __restrict__ bn_b,
    const float* __restrict__ bn_m, const float* __restrict__ bn_v,
    const float* __restrict__ w2, const float* __restrict__ b2,
    const float* __restrict__ w_k, const float* __restrict__ b_k,
    float* __restrict__ weight, float* __restrict__ bias) {
    const int b = blockIdx.x / 10;
    const int p = blockIdx.x % 10;   // 0..8 = pooled pixel, 9 = global mean
    const int tid = threadIdx.x;     // == channel c in the epilogue

    __shared__ __align__(16) float t[CC];
    __shared__ __align__(16) float hbuf[64];
    __shared__ float hpart[256];

    if (p < 9) {
        t[tid] = pooled[(b * CC + tid) * 9 + p];
    } else {
        float s = 0.f;
        #pragma unroll
        for (int q = 0; q < 9; ++q) s += pooled[(b * CC + tid) * 9 + q];
        t[tid] = s * (1.0f / 9.0f);
    }
    __syncthreads();

    // h = w1 @ t  (64 outputs, 4 partial-threads each), float4 dots
    const int o = tid & 63, part = tid >> 6;
    {
        const float4* w1r = (const float4*)(w1 + o * CC + part * 64);
        const float4* tp  = (const float4*)(t + part * 64);
        float acc = 0.f;
        #pragma unroll
        for (int k = 0; k < 16; ++k) {
            float4 a = w1r[k], v = tp[k];
            acc += a.x * v.x + a.y * v.y + a.z * v.z + a.w * v.w;
        }
        hpart[tid] = acc;
    }
    __syncthreads();
    if (tid < 64) {
        float hsum = hpart[tid] + hpart[tid + 64] + hpart[tid + 128] +
                     hpart[tid + 192] + b1[tid];
        float hn = (hsum - bn_m[tid]) * (bn_g[tid] * rsqrtf(bn_v[tid] + 1e-5f)) + bn_b[tid];
        hbuf[tid] = 0.5f * hn * (1.0f + erff(hn * 0.70710678118654752f));
    }
    __syncthreads();

    float vals[4];
    #pragma unroll
    for (int q = 0; q < 4; ++q) {
        const int j = q * 256 + tid;
        const float4* w2r = (const float4*)(w2 + j * 64);
        const float4* hb  = (const float4*)hbuf;
        float a = b2[j];
        #pragma unroll
        for (int k = 0; k < 16; ++k) {
            float4 wv = w2r[k], hv = hb[k];
            a += wv.x * hv.x + wv.y * hv.y + wv.z * hv.z + wv.w * hv.w;
        }
        vals[q] = a;
    }
    float m = fmaxf(fmaxf(vals[0], vals[1]), fmaxf(vals[2], vals[3]));
    float e[4], sum = 0.f;
    #pragma unroll
    for (int q = 0; q < 4; ++q) { e[q] = expf(vals[q] - m); sum += e[q]; }
    const float rinv = 1.0f / sum;

    if (p < 9) {
        float ws = 0.f;
        #pragma unroll
        for (int q = 0; q < 4; ++q)
            ws += (e[q] * rinv) * w_k[(q * CC + tid) * 9 + p];
        weight[(b * CC + tid) * 9 + p] = ws;
    } else {
        float bs = 0.f;
        #pragma unroll
        for (int q = 0; q < 4; ++q)
            bs += (e[q] * rinv) * b_k[q * CC + tid];
        bias[b * CC + tid] = bs;
    }
}

// ---------------- Kernel 3: dynamic depthwise 3x3 conv (SAME) + bias ---------
// LDS-free, 8x4 patches (TALLER, same 4-col width that measured best): 10 input
// rows serve 8 output rows -> vertical overfetch 1.25x (was 1.5x for 4x4),
// logical cache reads 9 -> 7.5 B/px, VMEM instrs/px 1.375 -> 1.19, and half
// the per-thread weight/bias broadcast loads. ~90 VGPR -> 6 blocks/CU.
// 288 patches per plane; 4096*288/256 = 4608 blocks, global patch indexing.
// x is L2/L3-hot after pool (R3 FETCH: no HBM re-read); NT stores to HBM.
__global__ __launch_bounds__(256) void dwconv_kernel(
    const float* __restrict__ x, const float* __restrict__ weight,
    const float* __restrict__ bias, float* __restrict__ out) {
    const int g  = blockIdx.x * 256 + threadIdx.x;   // global patch id
    const int bc = g / 288;                          // plane 0..4095
    const int p  = g - bc * 288;                     // patch in plane
    const int pr = p / 24;                           // patch row 0..11
    const int pc = p - pr * 24;                      // patch col 0..23
    const int h0 = pr * 8;                           // first output row
    const int c0 = pc * 4;                           // first output col (16B aligned)
    const float* plane = x + (size_t)bc * (HH * WW);
    float* oplane = out + (size_t)bc * (HH * WW);

    float wgt[9];
    #pragma unroll
    for (int k = 0; k < 9; ++k) wgt[k] = weight[bc * 9 + k];
    const float bs = bias[bc];

    // input rows h0-1 .. h0+8
    float4 m[10]; float L[10], R[10];
    #pragma unroll
    for (int r = 0; r < 10; ++r) {
        const int gr = h0 + r - 1;
        if (gr >= 0 && gr < HH) {
            const float* row = plane + gr * WW + c0;
            m[r] = *(const float4*)row;
            L[r] = (pc > 0)  ? row[-1] : 0.f;
            R[r] = (pc < 23) ? row[4]  : 0.f;
        } else {
            m[r] = make_float4(0.f, 0.f, 0.f, 0.f);
            L[r] = 0.f;
            R[r] = 0.f;
        }
    }

    #pragma unroll
    for (int orow = 0; orow < 8; ++orow) {
        floatx4 acc = {bs, bs, bs, bs};
        #pragma unroll
        for (int r = 0; r < 3; ++r) {
            const int rr = orow + r;
            const float wl = wgt[r * 3 + 0], wc = wgt[r * 3 + 1],
                        wr = wgt[r * 3 + 2];
            acc.x += wl * L[rr]   + wc * m[rr].x + wr * m[rr].y;
            acc.y += wl * m[rr].x + wc * m[rr].y + wr * m[rr].z;
            acc.z += wl * m[rr].y + wc * m[rr].z + wr * m[rr].w;
            acc.w += wl * m[rr].z + wc * m[rr].w + wr * R[rr];
        }
        __builtin_nontemporal_store(
            acc, (floatx4*)(oplane + (h0 + orow) * WW + c0));
    }
}

extern "C" void kernel_launch(void* const* d_in, const int* in_sizes, int n_in,
                              void* d_out, int out_size, void* d_ws, size_t ws_size,
                              hipStream_t stream) {
    const float* x    = (const float*)d_in[0];
    const float* w_k  = (const float*)d_in[1];
    const float* b_k  = (const float*)d_in[2];
    const float* w1   = (const float*)d_in[3];
    const float* b1   = (const float*)d_in[4];
    const float* bn_g = (const float*)d_in[5];
    const float* bn_b = (const float*)d_in[6];
    const float* bn_m = (const float*)d_in[7];
    const float* bn_v = (const float*)d_in[8];
    const float* w2   = (const float*)d_in[9];
    const float* b2   = (const float*)d_in[10];
    float* out = (float*)d_out;

    float* pooled = (float*)d_ws;                 // B*C*9 floats
    float* weight = pooled + BB * CC * 9;         // B*C*9 floats
    float* bias   = weight + BB * CC * 9;         // B*C   floats

    pool_kernel<<<BB * CC, 256, 0, stream>>>(x, pooled);
    proj_kernel<<<BB * 10, 256, 0, stream>>>(pooled, w1, b1, bn_g, bn_b, bn_m,
                                             bn_v, w2, b2, w_k, b_k, weight, bias);
    // 4096 planes * 288 patches / 256 threads = 4608 blocks
    dwconv_kernel<<<BB * CC * 288 / 256, 256, 0, stream>>>(x, weight, bias, out);
}